// Round 8
// baseline (215.723 us; speedup 1.0000x reference)
//
#include <hip/hip_runtime.h>
#include <hip/hip_bf16.h>

// VectorQuantize: B=16, D=256, T=4096, K=1024.
//   prep    : W -> fp16 (x1024) in chunk-linear MFMA layout, wsq[k]=512*||w_k||^2.
//   xprep   : x -> fp16 fragment layout xf16 (coalesced read + LDS transpose);
//             xf16 borrows d_out.
//   stageA  : 512 blocks x 256 thr (4 waves). B chunks staged through a 3x8KB
//             rotating LDS buffer via global_load_lds with COUNTED vmcnt(4) +
//             raw s_barrier (prefetch stays in flight across barriers; no
//             vmcnt(0) drain). Per-CU L2 B-traffic 1 MB (shared) vs 4 MB (per-wave).
//             mfma_f32_16x16x32_f16, rank, per-lane top-2 -> merge -> top-4/row.
//   stageBC : 2048 blocks x 32 rows, XLS=257, fp64 refine, winner/counts/loss.
//   finalize: vq_loss + perplexity.

#define DD   256
#define KK   1024
#define TT   4096
#define BBB  16
#define NROW (BBB*TT)

typedef _Float16 half8 __attribute__((ext_vector_type(8)));
typedef float f32x4 __attribute__((ext_vector_type(4)));

__device__ __forceinline__ unsigned umaxu(unsigned a, unsigned b) { return a > b ? a : b; }
__device__ __forceinline__ unsigned uminu(unsigned a, unsigned b) { return a < b ? a : b; }

// direct global->LDS 16B DMA: per-lane global src, LDS dst = wave-uniform base + lane*16
__device__ __forceinline__ void gl2lds16(const void* g, void* l) {
    __builtin_amdgcn_global_load_lds(
        (const __attribute__((address_space(1))) unsigned int*)g,
        (__attribute__((address_space(3))) unsigned int*)l,
        16, 0, 0);
}

// ---------------- prep ----------------
// dst layout (halves): (((chunk*8+ks)*4+q)*16+n)*8 + j ; k = chunk*16+n, d = ks*32+q*8+j.
__global__ void prep(const float* __restrict__ w, _Float16* __restrict__ w16,
                     unsigned* __restrict__ counts, double* __restrict__ lsum,
                     float* __restrict__ wsq) {
    int gid = blockIdx.x * 256 + threadIdx.x;      // 0..32767
    int k = gid >> 5;                              // code 0..1023
    int c = gid & 31;                              // d-chunk of 8
    int chunk = k >> 4, n = k & 15;
    int ks = c >> 2, q = c & 3;
    const float* src = w + (k << 8) + (c << 3);
    union { uint4 u; _Float16 h[8]; } pk;
#pragma unroll
    for (int j = 0; j < 8; ++j) pk.h[j] = (_Float16)(src[j] * 1024.0f);
    size_t dst = ((((size_t)chunk * 8 + ks) * 4 + q) * 16 + n) * 8;
    *(uint4*)(w16 + dst) = pk.u;
    if (c == 0) {
        const float4* wr4 = (const float4*)(w + (k << 8));
        float s = 0.f;
#pragma unroll 8
        for (int ii = 0; ii < 64; ++ii) {
            float4 v = wr4[ii];
            s += v.x * v.x + v.y * v.y + v.z * v.z + v.w * v.w;
        }
        wsq[k] = 512.0f * s;
    }
    if (gid < KK) counts[gid] = 0u;
    if (gid == KK) *lsum = 0.0;
}

// ---------------- xprep ----------------
// 2048 blocks x 256 threads. Block owns 32 t (one b). Coalesced float4 x-read ->
// LDS transpose -> f16 fragment layout xf16[((tgg*8+ks)*64+lane)*8 + j].
#define XPS 260
__global__ __launch_bounds__(256) void xprep(const float* __restrict__ x,
                                             _Float16* __restrict__ xf16) {
    __shared__ __align__(16) float xt[32 * XPS];   // 33.3 KB
    int tid = threadIdx.x, bid = blockIdx.x;
    int b = bid >> 7, t0 = (bid & 127) << 5;
    const float* xb = x + ((size_t)b << 20) + t0;

    {
        int dr = tid >> 3;                 // 0..31
        int t4 = (tid & 7) << 2;           // 0..28
#pragma unroll
        for (int pass = 0; pass < 8; ++pass) {
            int d = (pass << 5) + dr;
            float4 v = *(const float4*)(xb + ((size_t)d << 12) + t4);
            xt[(t4 + 0) * XPS + d] = v.x;
            xt[(t4 + 1) * XPS + d] = v.y;
            xt[(t4 + 2) * XPS + d] = v.z;
            xt[(t4 + 3) * XPS + d] = v.w;
        }
    }
    __syncthreads();

    int tgg0 = (b << 8) + (t0 >> 4);       // global tile-group base (2 per block)
#pragma unroll
    for (int f = 0; f < 4; ++f) {
        int idx = (f << 8) + tid;          // 0..1023
        int tg = idx >> 9;                 // 0..1
        int ks = (idx >> 6) & 7;
        int ln = idx & 63;
        int n2 = ln & 15, q2 = ln >> 4;
        int tl = (tg << 4) + n2;
        int db = (ks << 5) + (q2 << 3);
        float4 u0 = *(const float4*)(&xt[tl * XPS + db]);
        float4 u1 = *(const float4*)(&xt[tl * XPS + db + 4]);
        union { uint4 u; _Float16 h[8]; } pk;
        pk.h[0] = (_Float16)u0.x; pk.h[1] = (_Float16)u0.y;
        pk.h[2] = (_Float16)u0.z; pk.h[3] = (_Float16)u0.w;
        pk.h[4] = (_Float16)u1.x; pk.h[5] = (_Float16)u1.y;
        pk.h[6] = (_Float16)u1.z; pk.h[7] = (_Float16)u1.w;
        size_t dst = ((((size_t)(tgg0 + tg) << 3) + ks) * 64 + ln) << 3;
        *(uint4*)(xf16 + dst) = pk.u;
    }
}

// ---------------- stage A ----------------
// 512 blocks x 256 threads (4 waves). Block owns 128 rows (one b, 128 consecutive t).
// Wave wv owns rows [wv*32, wv*32+32) = two 16-row m-tiles.
// Chunk loop: STAGE(ch+2) -> s_waitcnt vmcnt(4) lgkmcnt(0) -> s_barrier (Bar_A:
// buf[ch%3] staged by all waves) -> compute ch -> lgkmcnt(0) -> s_barrier (Bar_B:
// all waves done reading buf[ch%3], so next iter may re-stage it).
// Race ledger: STAGE(ch+2) writes buf[(ch+2)%3], issued after Bar_B(ch-1) which
// retired all readers of that buffer (compute ch-1). In-flight landings during
// compute ch are st(ch+1),st(ch+2) -> buffers (ch+1)%3,(ch+2)%3 != ch%3.
// vmcnt(4): after issuing st(ch+2), <=4 outstanding == {st(ch+1),st(ch+2)} =>
// st(ch) fully landed. Tail wraps STAGE((ch+2)&63): targets never read again,
// keeps vmcnt immediate constant.

// stage chunk chn (wrapped) into bbuf[chn%3]: 2 x 16B DMA per thread
#define STAGE(chn) do {                                                        \
    const uint4* _s = wsrc + (((chn) & 63) << 9) + tid;                        \
    _Float16* _d = bbuf[(chn) % 3];                                            \
    gl2lds16(_s,       _d + (tid << 3));                                       \
    gl2lds16(_s + 256, _d + ((tid + 256) << 3));                               \
} while (0)

__global__ __launch_bounds__(256, 2) void stageA(const _Float16* __restrict__ xf16,
                                                 const _Float16* __restrict__ w16,
                                                 const float* __restrict__ wsq,
                                                 uint4* __restrict__ cand) {
    __shared__ __align__(16) float wsql[KK];              // 4 KB
    __shared__ __align__(16) _Float16 bbuf[3][4096];      // 3 x 8 KB rotating stage
    int tid = threadIdx.x, bid = blockIdx.x;
    int b = bid >> 5;
    int t0 = (bid & 31) << 7;

    int lane = tid & 63, wv = tid >> 6;
    int n = lane & 15, q = lane >> 4;

    const uint4* wsrc = (const uint4*)w16;

    // A fragments first (oldest vmem ops -> drained by iter-0's vmcnt(4))
    half8 afrag[2][8];
#pragma unroll
    for (int mt = 0; mt < 2; ++mt) {
        int tgg = (b << 8) + (t0 >> 4) + (wv << 1) + mt;
#pragma unroll
        for (int ks = 0; ks < 8; ++ks) {
            const _Float16* ap = xf16 + (((((size_t)tgg << 3) + ks) * 64 + lane) << 3);
            afrag[mt][ks] = *(const half8*)ap;
        }
    }
    ((float4*)wsql)[tid] = ((const float4*)wsq)[tid];   // global ld + ds_write

    STAGE(0);
    STAGE(1);

    unsigned b1[8], b2[8];
#pragma unroll
    for (int i = 0; i < 8; ++i) { b1[i] = 0u; b2[i] = 0u; }

    for (int ch = 0; ch < 64; ++ch) {
        STAGE(ch + 2);
        asm volatile("s_waitcnt vmcnt(4) lgkmcnt(0)" ::: "memory");
        __builtin_amdgcn_s_barrier();        // Bar_A: bbuf[ch%3] fully staged
        {
            const _Float16* bb = bbuf[ch % 3];
            half8 bfr[8];
#pragma unroll
            for (int ks = 0; ks < 8; ++ks)
                bfr[ks] = *(const half8*)(bb + (ks << 9) + (lane << 3));
            f32x4 a0 = {0.f, 0.f, 0.f, 0.f};
            f32x4 a1 = {0.f, 0.f, 0.f, 0.f};
#pragma unroll
            for (int ks = 0; ks < 8; ++ks) {
                a0 = __builtin_amdgcn_mfma_f32_16x16x32_f16(afrag[0][ks], bfr[ks], a0, 0, 0, 0);
                a1 = __builtin_amdgcn_mfma_f32_16x16x32_f16(afrag[1][ks], bfr[ks], a1, 0, 0, 0);
            }
            unsigned kg = (unsigned)((ch << 4) + n);
            float csub = wsql[kg];
#pragma unroll
            for (int i = 0; i < 4; ++i) {
                float v; unsigned p, o;
                v = fmaxf(a0[i] - csub, 0.0f);
                p = (__float_as_uint(v) & 0xFFFFFC00u) | kg;
                o = b1[i];
                b2[i] = umaxu(b2[i], uminu(p, o));
                b1[i] = umaxu(o, p);
                v = fmaxf(a1[i] - csub, 0.0f);
                p = (__float_as_uint(v) & 0xFFFFFC00u) | kg;
                o = b1[4 + i];
                b2[4 + i] = umaxu(b2[4 + i], uminu(p, o));
                b1[4 + i] = umaxu(o, p);
            }
        }
        asm volatile("s_waitcnt lgkmcnt(0)" ::: "memory");
        __builtin_amdgcn_s_barrier();        // Bar_B: bbuf[ch%3] free for re-stage
    }

    // merge the 16 column-lanes' top-2 -> per-row top-4
#pragma unroll
    for (int s = 0; s < 8; ++s) {
        unsigned v0 = b1[s], v1 = b2[s], v2 = 0u, v3 = 0u;
#pragma unroll
        for (int m = 1; m <= 8; m <<= 1) {
            unsigned e0 = __shfl_xor(v0, m);
            unsigned e1 = __shfl_xor(v1, m);
            unsigned e2 = __shfl_xor(v2, m);
            unsigned e3 = __shfl_xor(v3, m);
#pragma unroll
            for (int u = 0; u < 4; ++u) {
                unsigned e = (u == 0) ? e0 : (u == 1) ? e1 : (u == 2) ? e2 : e3;
                unsigned t;
                t = umaxu(e, v0); e = uminu(e, v0); v0 = t;
                t = umaxu(e, v1); e = uminu(e, v1); v1 = t;
                t = umaxu(e, v2); e = uminu(e, v2); v2 = t;
                v3 = umaxu(e, v3);
            }
        }
        if (n == 0) {
            int row_local = (wv << 5) + ((s >> 2) << 4) + (q << 2) + (s & 3);
            cand[(bid << 7) + row_local] = make_uint4(v0, v1, v2, v3);
        }
    }
}

// ---------------- stage B+C ----------------
// 2048 blocks x 256 threads (4 waves). Block owns 32 rows (one b, 32 consecutive t).
#define XLS 257   // 257 % 32 == 1 -> conflict-free transpose
__global__ __launch_bounds__(256) void stageBC(const float* __restrict__ x,
                                               const float* __restrict__ w,
                                               const uint4* __restrict__ cand,
                                               float* __restrict__ out,
                                               unsigned* __restrict__ counts,
                                               double* __restrict__ lsum) {
    __shared__ __align__(16) float xl[32 * XLS];   // 32.9 KB; reused as w-gather
    __shared__ double disl[32][4];
    __shared__ int winner[32];
    __shared__ double ldis[32];
    int tid = threadIdx.x, bid = blockIdx.x;
    int b = bid >> 7, t0 = (bid & 127) << 5;
    int lane = tid & 63, wv = tid >> 6;

    // phase L: coalesced x tile -> LDS transposed [t][d], stride XLS
    {
        int dr = tid >> 3;                 // 0..31
        int t4 = (tid & 7) << 2;           // 0..28
        const float* xb = x + ((size_t)b << 20) + t0 + t4;
#pragma unroll
        for (int pass = 0; pass < 8; ++pass) {
            int d = (pass << 5) + dr;
            float4 v = *(const float4*)(xb + ((size_t)d << 12));
            xl[(t4 + 0) * XLS + d] = v.x;
            xl[(t4 + 1) * XLS + d] = v.y;
            xl[(t4 + 2) * XLS + d] = v.z;
            xl[(t4 + 3) * XLS + d] = v.w;
        }
    }
    __syncthreads();

    // phase R: fp64 distances; c = lane>>4 (candidate), dl = lane&15 (d chunk)
    int c = lane >> 4, dl = lane & 15;
#pragma unroll
    for (int rr = 0; rr < 8; ++rr) {
        int r = (wv << 3) + rr;
        int rowg = (b << 12) + t0 + r;
        unsigned ci = ((const unsigned*)cand)[((size_t)rowg << 2) + c] & 1023u;
        const float* wr = w + (ci << 8);
        double s = 0.0;
#pragma unroll
        for (int dd = 0; dd < 4; ++dd) {
            int d4 = (dd << 6) + (dl << 2);
            float4 xv = *(const float4*)(&xl[r * XLS + d4]);
            float4 wv4 = *(const float4*)(wr + d4);
            double e;
            e = (double)xv.x - (double)wv4.x; s = fma(e, e, s);
            e = (double)xv.y - (double)wv4.y; s = fma(e, e, s);
            e = (double)xv.z - (double)wv4.z; s = fma(e, e, s);
            e = (double)xv.w - (double)wv4.w; s = fma(e, e, s);
        }
#pragma unroll
        for (int m = 1; m <= 8; m <<= 1) s += __shfl_xor(s, m);
        if (dl == 0) disl[r][c] = s;
    }
    __syncthreads();

    // winner selection (tie -> smaller index)
    if (tid < 32) {
        int rowg = (b << 12) + t0 + tid;
        uint4 cc = cand[rowg];
        unsigned i0 = cc.x & 1023u, i1 = cc.y & 1023u, i2 = cc.z & 1023u, i3 = cc.w & 1023u;
        double dm = disl[tid][0]; unsigned ci = i0;
        double dk;
        dk = disl[tid][1]; if (dk < dm || (dk == dm && i1 < ci)) { dm = dk; ci = i1; }
        dk = disl[tid][2]; if (dk < dm || (dk == dm && i2 < ci)) { dm = dk; ci = i2; }
        dk = disl[tid][3]; if (dk < dm || (dk == dm && i3 < ci)) { dm = dk; ci = i3; }
        winner[tid] = (int)ci;
        ldis[tid] = dm;
        atomicAdd(&counts[ci], 1u);
    }
    __syncthreads();

    // gather winner w rows into LDS (reuse xl): one coalesced 1KB row per wave-instr
    float* wg = xl;
#pragma unroll
    for (int rp = 0; rp < 8; ++rp) {
        int r = (rp << 2) + wv;
        int win = winner[r];
        *(float4*)(&wg[r * XLS + (lane << 2)]) =
            *(const float4*)(w + (win << 8) + (lane << 2));
    }
    __syncthreads();

    // emit: out[b][d][t0+t] = wg[t][d], coalesced float4 along t
    {
        int dr = tid >> 3;                 // 0..31
        int t4 = (tid & 7) << 2;
        float* ob = out + ((size_t)b << 20) + t0 + t4;
#pragma unroll
        for (int pass = 0; pass < 8; ++pass) {
            int d = (pass << 5) + dr;
            float4 o;
            o.x = wg[(t4 + 0) * XLS + d];
            o.y = wg[(t4 + 1) * XLS + d];
            o.z = wg[(t4 + 2) * XLS + d];
            o.w = wg[(t4 + 3) * XLS + d];
            *(float4*)(ob + ((size_t)d << 12)) = o;
        }
    }

    // loss reduction
    __syncthreads();
    if (tid < 16) ldis[tid] += ldis[tid + 16];
    __syncthreads();
    if (tid < 8) ldis[tid] += ldis[tid + 8];
    __syncthreads();
    if (tid < 4) ldis[tid] += ldis[tid + 4];
    __syncthreads();
    if (tid < 2) ldis[tid] += ldis[tid + 2];
    __syncthreads();
    if (tid == 0) atomicAdd(lsum, ldis[0] + ldis[1]);
}

// ---------------- finalize ----------------
__global__ void finalize(const unsigned* __restrict__ counts,
                         const double* __restrict__ lsum,
                         float* __restrict__ out2) {
    __shared__ double part[256];
    int tid = threadIdx.x;
    double s = 0.0;
    for (int i = tid; i < KK; i += 256) {
        double p = (double)counts[i] / (double)NROW;
        s += p * log(p + 1e-10);
    }
    part[tid] = s;
    __syncthreads();
    for (int st = 128; st > 0; st >>= 1) {
        if (tid < st) part[tid] += part[tid + st];
        __syncthreads();
    }
    if (tid == 0) {
        out2[0] = (float)(1.25 * (*lsum) / ((double)NROW * (double)DD));
        out2[1] = (float)exp(-part[0]);
    }
}

extern "C" void kernel_launch(void* const* d_in, const int* in_sizes, int n_in,
                              void* d_out, int out_size, void* d_ws, size_t ws_size,
                              hipStream_t stream) {
    const float* x = (const float*)d_in[0];
    const float* w = (const float*)d_in[1];
    float* out = (float*)d_out;
    char* ws = (char*)d_ws;
    _Float16* w16    = (_Float16*)ws;                         // 524288 B
    uint4*    cnd    = (uint4*)(ws + 524288);                 // 1 MB
    unsigned* counts = (unsigned*)(ws + 1572864);             // 4 KB
    float*    wsq    = (float*)(ws + 1576960);                // 4 KB
    double*   lsum   = (double*)(ws + 1581056);               // 8 B
    // xf16 (33.5 MB) borrows d_out's buffer: stageBC only WRITES out (never reads),
    // after the last xf16 read (stageA) completed on the stream.
    _Float16* xf16   = (_Float16*)d_out;

    prep<<<128, 256, 0, stream>>>(w, w16, counts, lsum, wsq);
    xprep<<<2048, 256, 0, stream>>>(x, xf16);
    stageA<<<512, 256, 0, stream>>>(xf16, w16, wsq, (uint4*)cnd);
    stageBC<<<2048, 256, 0, stream>>>(x, w, (const uint4*)cnd, out, counts, lsum);
    finalize<<<1, 256, 0, stream>>>(counts, lsum, out + (size_t)NROW * DD);
}

// Round 10
// 186.545 us; speedup vs baseline: 1.1564x; 1.1564x over previous
//
#include <hip/hip_runtime.h>
#include <hip/hip_bf16.h>

// VectorQuantize: B=16, D=256, T=4096, K=1024.  FUSED pipeline (3 kernels):
//   prep    : W -> fp16 (x1024) chunk-linear MFMA layout, wsq[k]=512*||w_k||^2,
//             zero counts/lsum.
//   fused   : 512 blocks x 256 thr (4 waves), block owns 128 rows (one b).
//             P0: x quarter-tiles (32 t) -> LDS transpose -> afrag (fp16, regs).
//             P1: rank vs all 1024 codes, barrier-free reg-stream double buffer
//                 (round-7 validated loop), top-4/row -> cand in LDS.
//             P2: 4 quarters: x re-read (L2-hot) -> fp64 refine of 4 cands ->
//                 winner/counts/loss -> w-gather -> coalesced out emit.
//   finalize: vq_loss + perplexity.
// Eliminates xf16 round-trip (67 MB), second full x HBM read, 2 launch gaps.

#define DD   256
#define KK   1024
#define TT   4096
#define BBB  16
#define NROW (BBB*TT)

typedef _Float16 half8 __attribute__((ext_vector_type(8)));
typedef float f32x4 __attribute__((ext_vector_type(4)));

__device__ __forceinline__ unsigned umaxu(unsigned a, unsigned b) { return a > b ? a : b; }
__device__ __forceinline__ unsigned uminu(unsigned a, unsigned b) { return a < b ? a : b; }

// ---------------- prep ----------------
// dst layout (halves): (((chunk*8+ks)*4+q)*16+n)*8 + j ; k = chunk*16+n, d = ks*32+q*8+j.
__global__ void prep(const float* __restrict__ w, _Float16* __restrict__ w16,
                     unsigned* __restrict__ counts, double* __restrict__ lsum,
                     float* __restrict__ wsq) {
    int gid = blockIdx.x * 256 + threadIdx.x;      // 0..32767
    int k = gid >> 5;                              // code 0..1023
    int c = gid & 31;                              // d-chunk of 8
    int chunk = k >> 4, n = k & 15;
    int ks = c >> 2, q = c & 3;
    const float* src = w + (k << 8) + (c << 3);
    union { uint4 u; _Float16 h[8]; } pk;
#pragma unroll
    for (int j = 0; j < 8; ++j) pk.h[j] = (_Float16)(src[j] * 1024.0f);
    size_t dst = ((((size_t)chunk * 8 + ks) * 4 + q) * 16 + n) * 8;
    *(uint4*)(w16 + dst) = pk.u;
    if (c == 0) {
        const float4* wr4 = (const float4*)(w + (k << 8));
        float s = 0.f;
#pragma unroll 8
        for (int ii = 0; ii < 64; ++ii) {
            float4 v = wr4[ii];
            s += v.x * v.x + v.y * v.y + v.z * v.z + v.w * v.w;
        }
        wsq[k] = 512.0f * s;
    }
    if (gid < KK) counts[gid] = 0u;
    if (gid == KK) *lsum = 0.0;
}

// ---------------- fused ----------------
#define XLS 257   // validated stageBC stride (257 % 32 == 1)

// coalesced x 32-t quarter load -> LDS transposed [t][d] (stageBC phase-L verbatim)
#define XLOAD(toff) do {                                                       \
    int _dr = tid >> 3;                                                        \
    int _t4 = (tid & 7) << 2;                                                  \
    const float* _xb = x + ((size_t)b << 20) + t0 + (toff) + _t4;              \
    _Pragma("unroll")                                                          \
    for (int _pass = 0; _pass < 8; ++_pass) {                                  \
        int _d = (_pass << 5) + _dr;                                           \
        float4 _v = *(const float4*)(_xb + ((size_t)_d << 12));                \
        xt[(_t4 + 0) * XLS + _d] = _v.x;                                       \
        xt[(_t4 + 1) * XLS + _d] = _v.y;                                       \
        xt[(_t4 + 2) * XLS + _d] = _v.z;                                       \
        xt[(_t4 + 3) * XLS + _d] = _v.w;                                       \
    }                                                                          \
} while (0)

// load chunk `chn`'s 8 k-slices into named half8 regs PFX0..PFX7 (round-7 verbatim)
#define LOADB(PFX, chn) do {                                                   \
    const uint4* _p = wsrc + ((chn) << 9) + lane;                              \
    PFX##0 = *(const half8*)(_p);                                              \
    PFX##1 = *(const half8*)(_p + 64);                                         \
    PFX##2 = *(const half8*)(_p + 128);                                        \
    PFX##3 = *(const half8*)(_p + 192);                                        \
    PFX##4 = *(const half8*)(_p + 256);                                        \
    PFX##5 = *(const half8*)(_p + 320);                                        \
    PFX##6 = *(const half8*)(_p + 384);                                        \
    PFX##7 = *(const half8*)(_p + 448);                                        \
} while (0)

#define MFMA16(A, B, C) __builtin_amdgcn_mfma_f32_16x16x32_f16((A), (B), (C), 0, 0, 0)

// compute chunk `ch` against named regs PFX0..PFX7, update b1/b2 (round-7 verbatim)
#define COMPUTE(ch, PFX) do {                                                  \
    f32x4 a0 = {0.f, 0.f, 0.f, 0.f};                                           \
    f32x4 a1 = {0.f, 0.f, 0.f, 0.f};                                           \
    a0 = MFMA16(afrag[0][0], PFX##0, a0); a1 = MFMA16(afrag[1][0], PFX##0, a1);\
    a0 = MFMA16(afrag[0][1], PFX##1, a0); a1 = MFMA16(afrag[1][1], PFX##1, a1);\
    a0 = MFMA16(afrag[0][2], PFX##2, a0); a1 = MFMA16(afrag[1][2], PFX##2, a1);\
    a0 = MFMA16(afrag[0][3], PFX##3, a0); a1 = MFMA16(afrag[1][3], PFX##3, a1);\
    a0 = MFMA16(afrag[0][4], PFX##4, a0); a1 = MFMA16(afrag[1][4], PFX##4, a1);\
    a0 = MFMA16(afrag[0][5], PFX##5, a0); a1 = MFMA16(afrag[1][5], PFX##5, a1);\
    a0 = MFMA16(afrag[0][6], PFX##6, a0); a1 = MFMA16(afrag[1][6], PFX##6, a1);\
    a0 = MFMA16(afrag[0][7], PFX##7, a0); a1 = MFMA16(afrag[1][7], PFX##7, a1);\
    unsigned kg = (unsigned)(((ch) << 4) + n);                                 \
    float csub = wsql[kg];                                                     \
    _Pragma("unroll")                                                          \
    for (int i = 0; i < 4; ++i) {                                              \
        float v; unsigned p, o;                                                \
        v = fmaxf(a0[i] - csub, 0.0f);                                         \
        p = (__float_as_uint(v) & 0xFFFFFC00u) | kg;                           \
        o = b1[i];                                                             \
        b2[i] = umaxu(b2[i], uminu(p, o));                                     \
        b1[i] = umaxu(o, p);                                                   \
        v = fmaxf(a1[i] - csub, 0.0f);                                         \
        p = (__float_as_uint(v) & 0xFFFFFC00u) | kg;                           \
        o = b1[4 + i];                                                         \
        b2[4 + i] = umaxu(b2[4 + i], uminu(p, o));                             \
        b1[4 + i] = umaxu(o, p);                                               \
    }                                                                          \
} while (0)

__global__ __launch_bounds__(256, 2) void fused(const float* __restrict__ x,
                                                const float* __restrict__ w,
                                                const _Float16* __restrict__ w16,
                                                const float* __restrict__ wsq,
                                                float* __restrict__ out,
                                                unsigned* __restrict__ counts,
                                                double* __restrict__ lsum) {
    __shared__ __align__(16) float xt[32 * XLS];   // 32.9 KB; x quarter / w-gather
    __shared__ __align__(16) float wsql[KK];       // 4 KB
    __shared__ __align__(16) uint4 cndl[128];      // 2 KB: top-4 per row
    __shared__ double disl[32][4];
    __shared__ int winner[32];
    __shared__ double ldis[32];

    int tid = threadIdx.x, bid = blockIdx.x;
    int b = bid >> 5;
    int t0 = (bid & 31) << 7;                      // 128 rows per block
    int lane = tid & 63, wv = tid >> 6;
    int n = lane & 15, q = lane >> 4;

    ((float4*)wsql)[tid] = ((const float4*)wsq)[tid];

    // ---- P0: 4 quarter-loads; wave p extracts its afrag from quarter p ----
    half8 afrag[2][8];
#pragma unroll
    for (int p = 0; p < 4; ++p) {
        XLOAD(p << 5);
        __syncthreads();
        if (wv == p) {
#pragma unroll
            for (int mt = 0; mt < 2; ++mt) {
                int rl = (mt << 4) + n;            // t-local row within quarter
#pragma unroll
                for (int ks = 0; ks < 8; ++ks) {
                    const float* sp = &xt[rl * XLS + (ks << 5) + (q << 3)];
                    half8 f;
#pragma unroll
                    for (int j = 0; j < 8; ++j) f[j] = (_Float16)sp[j];
                    afrag[mt][ks] = f;
                }
            }
        }
        __syncthreads();
    }

    // ---- P1: rank (round-7 barrier-free reg-stream) ----
    unsigned b1[8], b2[8];
#pragma unroll
    for (int i = 0; i < 8; ++i) { b1[i] = 0u; b2[i] = 0u; }

    const uint4* wsrc = (const uint4*)w16;
    half8 bA0, bA1, bA2, bA3, bA4, bA5, bA6, bA7;
    half8 bB0, bB1, bB2, bB3, bB4, bB5, bB6, bB7;

    LOADB(bA, 0);
    for (int ch = 0; ch < 64; ch += 2) {
        LOADB(bB, ch + 1);
        COMPUTE(ch, bA);
        if (ch + 2 < 64) LOADB(bA, ch + 2);
        COMPUTE(ch + 1, bB);
    }

    // merge the 16 column-lanes' top-2 -> per-row top-4 -> cndl (LDS)
#pragma unroll
    for (int s = 0; s < 8; ++s) {
        unsigned v0 = b1[s], v1 = b2[s], v2 = 0u, v3 = 0u;
#pragma unroll
        for (int m = 1; m <= 8; m <<= 1) {
            unsigned e0 = __shfl_xor(v0, m);
            unsigned e1 = __shfl_xor(v1, m);
            unsigned e2 = __shfl_xor(v2, m);
            unsigned e3 = __shfl_xor(v3, m);
#pragma unroll
            for (int u = 0; u < 4; ++u) {
                unsigned e = (u == 0) ? e0 : (u == 1) ? e1 : (u == 2) ? e2 : e3;
                unsigned t;
                t = umaxu(e, v0); e = uminu(e, v0); v0 = t;
                t = umaxu(e, v1); e = uminu(e, v1); v1 = t;
                t = umaxu(e, v2); e = uminu(e, v2); v2 = t;
                v3 = umaxu(e, v3);
            }
        }
        if (n == 0) {
            int row_local = (wv << 5) + ((s >> 2) << 4) + (q << 2) + (s & 3);
            cndl[row_local] = make_uint4(v0, v1, v2, v3);
        }
    }
    __syncthreads();

    // ---- P2: 4 quarters of {x reload, fp64 refine, winner, gather, emit, loss} ----
    int c = lane >> 4, dl = lane & 15;
    for (int qt = 0; qt < 4; ++qt) {
        XLOAD(qt << 5);                            // L2-hot re-read
        __syncthreads();

        // refine (stageBC phase R verbatim; cand from LDS)
#pragma unroll
        for (int rr = 0; rr < 8; ++rr) {
            int r = (wv << 3) + rr;
            unsigned ci = ((const unsigned*)cndl)[(((qt << 5) + r) << 2) + c] & 1023u;
            const float* wr = w + (ci << 8);
            double s = 0.0;
#pragma unroll
            for (int dd = 0; dd < 4; ++dd) {
                int d4 = (dd << 6) + (dl << 2);
                float4 xv = *(const float4*)(&xt[r * XLS + d4]);
                float4 wv4 = *(const float4*)(wr + d4);
                double e;
                e = (double)xv.x - (double)wv4.x; s = fma(e, e, s);
                e = (double)xv.y - (double)wv4.y; s = fma(e, e, s);
                e = (double)xv.z - (double)wv4.z; s = fma(e, e, s);
                e = (double)xv.w - (double)wv4.w; s = fma(e, e, s);
            }
#pragma unroll
            for (int m = 1; m <= 8; m <<= 1) s += __shfl_xor(s, m);
            if (dl == 0) disl[r][c] = s;
        }
        __syncthreads();

        // winner selection (tie -> smaller index), counts, per-row loss
        if (tid < 32) {
            uint4 cc = cndl[(qt << 5) + tid];
            unsigned i0 = cc.x & 1023u, i1 = cc.y & 1023u, i2 = cc.z & 1023u, i3 = cc.w & 1023u;
            double dm = disl[tid][0]; unsigned ci = i0;
            double dk;
            dk = disl[tid][1]; if (dk < dm || (dk == dm && i1 < ci)) { dm = dk; ci = i1; }
            dk = disl[tid][2]; if (dk < dm || (dk == dm && i2 < ci)) { dm = dk; ci = i2; }
            dk = disl[tid][3]; if (dk < dm || (dk == dm && i3 < ci)) { dm = dk; ci = i3; }
            winner[tid] = (int)ci;
            ldis[tid] = dm;
            atomicAdd(&counts[ci], 1u);
        }
        __syncthreads();

        // gather winner w rows into LDS (reuse xt)
#pragma unroll
        for (int rp = 0; rp < 8; ++rp) {
            int r = (rp << 2) + wv;
            int win = winner[r];
            *(float4*)(&xt[r * XLS + (lane << 2)]) =
                *(const float4*)(w + (win << 8) + (lane << 2));
        }
        __syncthreads();

        // emit: out[b][d][t0+qt*32+t] = xt[t][d], coalesced float4 along t
        {
            int dr = tid >> 3;
            int t4 = (tid & 7) << 2;
            float* ob = out + ((size_t)b << 20) + t0 + (qt << 5) + t4;
#pragma unroll
            for (int pass = 0; pass < 8; ++pass) {
                int d = (pass << 5) + dr;
                float4 o;
                o.x = xt[(t4 + 0) * XLS + d];
                o.y = xt[(t4 + 1) * XLS + d];
                o.z = xt[(t4 + 2) * XLS + d];
                o.w = xt[(t4 + 3) * XLS + d];
                *(float4*)(ob + ((size_t)d << 12)) = o;
            }
        }

        // loss reduction (stageBC verbatim)
        __syncthreads();
        if (tid < 16) ldis[tid] += ldis[tid + 16];
        __syncthreads();
        if (tid < 8) ldis[tid] += ldis[tid + 8];
        __syncthreads();
        if (tid < 4) ldis[tid] += ldis[tid + 4];
        __syncthreads();
        if (tid < 2) ldis[tid] += ldis[tid + 2];
        __syncthreads();
        if (tid == 0) atomicAdd(lsum, ldis[0] + ldis[1]);
        __syncthreads();                            // protect xt/ldis for next quarter
    }
}

// ---------------- finalize ----------------
__global__ void finalize(const unsigned* __restrict__ counts,
                         const double* __restrict__ lsum,
                         float* __restrict__ out2) {
    __shared__ double part[256];
    int tid = threadIdx.x;
    double s = 0.0;
    for (int i = tid; i < KK; i += 256) {
        double p = (double)counts[i] / (double)NROW;
        s += p * log(p + 1e-10);
    }
    part[tid] = s;
    __syncthreads();
    for (int st = 128; st > 0; st >>= 1) {
        if (tid < st) part[tid] += part[tid + st];
        __syncthreads();
    }
    if (tid == 0) {
        out2[0] = (float)(1.25 * (*lsum) / ((double)NROW * (double)DD));
        out2[1] = (float)exp(-part[0]);
    }
}

extern "C" void kernel_launch(void* const* d_in, const int* in_sizes, int n_in,
                              void* d_out, int out_size, void* d_ws, size_t ws_size,
                              hipStream_t stream) {
    const float* x = (const float*)d_in[0];
    const float* w = (const float*)d_in[1];
    float* out = (float*)d_out;
    char* ws = (char*)d_ws;
    _Float16* w16    = (_Float16*)ws;                         // 524288 B
    unsigned* counts = (unsigned*)(ws + 524288);              // 4 KB
    float*    wsq    = (float*)(ws + 528384);                 // 4 KB
    double*   lsum   = (double*)(ws + 532480);                // 8 B

    prep<<<128, 256, 0, stream>>>(w, w16, counts, lsum, wsq);
    fused<<<512, 256, 0, stream>>>(x, w, w16, wsq, out, counts, lsum);
    finalize<<<1, 256, 0, stream>>>(counts, lsum, out + (size_t)NROW * DD);
}